// Round 10
// baseline (91.117 us; speedup 1.0000x reference)
//
#include <hip/hip_runtime.h>
#include <hip/hip_bf16.h>
#include <stdint.h>

#define EPS 1e-5f

typedef __attribute__((ext_vector_type(8))) short short8;
typedef __attribute__((ext_vector_type(4))) float f32x4;

typedef const __attribute__((address_space(1))) uint32_t gas_u32;
typedef __attribute__((address_space(3))) uint32_t las_u32;

static __device__ __forceinline__ void gll16(const void* src, void* dst) {
    __builtin_amdgcn_global_load_lds((gas_u32*)src, (las_u32*)dst, 16, 0, 0);
}
static __device__ __forceinline__ unsigned short f2b(float f) {
    __hip_bfloat16 h = __float2bfloat16(f);
    return *reinterpret_cast<unsigned short*>(&h);
}
static __device__ __forceinline__ float b2f(unsigned short u) {
    union { unsigned int i; float f; } x; x.i = ((unsigned int)u) << 16; return x.f;
}
static __device__ __forceinline__ unsigned int pk2(float a, float b) {
    return (unsigned int)f2b(a) | ((unsigned int)f2b(b) << 16);
}

// ===========================================================================
// k_prep — simple/scalar version (R9):
//  BW[o][33][256] bf16 : rows 0..31 = W2[o,:,h] over i (w2T), row 32 = b2[o,:]
//  BQ[o][34][32]  bf16 : rows 0..31 = Q2[o,hp,:], row 32 = 2*P2, row 33 = S2
//  qb2f[o], sb2f[o] f32
// ===========================================================================
__global__ __launch_bounds__(256)
void k_prep(const float* __restrict__ w2, const float* __restrict__ b2,
            unsigned short* __restrict__ BW, unsigned short* __restrict__ BQ,
            float* __restrict__ qb2f, float* __restrict__ sb2f)
{
    __shared__ __align__(16) float w2s[256 * 32];   // [i][h]
    __shared__ __align__(16) float b2s[256];

    const int tid = threadIdx.x, lane = tid & 63, wave = tid >> 6;
    const int o = blockIdx.x;
    const float* w2o = w2 + (size_t)o * 8192;

    #pragma unroll
    for (int q = 0; q < 8; ++q) {
        int I = wave * 8 + q;
        gll16(w2o + I * 256 + lane * 4, w2s + I * 256);
    }
    if (wave == 0) gll16(b2 + (size_t)o * 256 + lane * 4, b2s);
    asm volatile("s_waitcnt vmcnt(0)" ::: "memory");
    __syncthreads();

    // ---- BW rows: r<32: BW[o][r][i] = w2s[i][r]; r==32: b2 ----
    for (int k = 0; k < 5; ++k) {
        int u = tid + k * 256;
        if (u < 1056) {                 // 33 rows x 32 uint4-units
            int r = u >> 5, s = u & 31;
            float vv[8];
            #pragma unroll
            for (int d = 0; d < 8; ++d)
                vv[d] = (r < 32) ? w2s[(s * 8 + d) * 32 + r] : b2s[s * 8 + d];
            uint4 pk;
            pk.x = pk2(vv[0], vv[1]); pk.y = pk2(vv[2], vv[3]);
            pk.z = pk2(vv[4], vv[5]); pk.w = pk2(vv[6], vv[7]);
            *(uint4*)&BW[((size_t)o * 33 + r) * 256 + s * 8] = pk;
        }
    }

    // ---- BQ rows 0..31: Q2[hp][h] = sum_i W2[i,hp] W2[i,h] ----
    {
        const int h = tid & 31, hp0 = tid >> 5;     // h fixed per thread
        float acc[4] = {0.f, 0.f, 0.f, 0.f};
        for (int i = 0; i < 256; ++i) {
            float wh = w2s[i * 32 + h];
            #pragma unroll
            for (int k = 0; k < 4; ++k)
                acc[k] += w2s[i * 32 + hp0 + 8 * k] * wh;
        }
        #pragma unroll
        for (int k = 0; k < 4; ++k)
            BQ[((size_t)o * 34 + (hp0 + 8 * k)) * 32 + h] = f2b(acc[k]);
    }

    // ---- BQ row 32 = 2*P2, row 33 = S2; qb2/sb2 scalars ----
    if (tid < 32) {
        float pa = 0.f, sa = 0.f;
        for (int i = 0; i < 256; ++i) {
            float wv = w2s[i * 32 + tid];
            pa += wv * b2s[i];
            sa += wv;
        }
        BQ[((size_t)o * 34 + 32) * 32 + tid] = f2b(2.0f * pa);
        BQ[((size_t)o * 34 + 33) * 32 + tid] = f2b(sa);
    } else if (tid == 32) {
        float sb = 0.f, qb = 0.f;
        for (int i = 0; i < 256; ++i) { float bv = b2s[i]; sb += bv; qb += bv * bv; }
        sb2f[o] = sb;
        qb2f[o] = qb;
    }
}

// ===========================================================================
// ka: per token (64-thr block): xbf, hwbf, sxf, blnbf (bias-path LN)
// ===========================================================================
__global__ __launch_bounds__(64)
void ka_hw_bias(const float* __restrict__ x,
                const float* __restrict__ w1, const float* __restrict__ b1,
                const float* __restrict__ u1, const float* __restrict__ c1,
                const float* __restrict__ u2, const float* __restrict__ c2,
                unsigned short* __restrict__ xbf,   // [T][256]
                unsigned short* __restrict__ hwbf,  // [T][32]
                float* __restrict__ sxf,            // [T]
                unsigned short* __restrict__ blnbf) // [T][256]
{
    const int t = blockIdx.x;
    const int l = threadIdx.x;

    __shared__ float xs[256];
    __shared__ float hb[32];

    float4 x4 = reinterpret_cast<const float4*>(x + (size_t)t * 256)[l];
    reinterpret_cast<float4*>(xs)[l] = x4;

    float s = x4.x + x4.y + x4.z + x4.w;
    #pragma unroll
    for (int off = 32; off > 0; off >>= 1) s += __shfl_xor(s, off);
    if (l == 0) sxf[t] = s;

    {
        ushort4 ux;
        ux.x = f2b(x4.x); ux.y = f2b(x4.y); ux.z = f2b(x4.z); ux.w = f2b(x4.w);
        *reinterpret_cast<ushort4*>(xbf + (size_t)t * 256 + l * 4) = ux;
    }
    __syncthreads();

    const float* wrow = (l < 32) ? (w1 + (size_t)l * 256) : (u1 + (size_t)(l - 32) * 256);
    float acc = (l < 32) ? b1[l] : c1[l - 32];
    #pragma unroll 8
    for (int i = 0; i < 256; i += 4) {
        float4 w = *reinterpret_cast<const float4*>(wrow + i);
        acc += w.x * xs[i] + w.y * xs[i + 1] + w.z * xs[i + 2] + w.w * xs[i + 3];
    }
    if (l < 32) hwbf[(size_t)t * 32 + l] = f2b(acc);
    else        hb[l - 32] = acc;
    __syncthreads();

    float bv[4];
    #pragma unroll
    for (int r = 0; r < 4; ++r) {
        const int oo = l * 4 + r;
        const float* urow = u2 + (size_t)oo * 32;
        float a = c2[oo];
        #pragma unroll
        for (int h = 0; h < 32; h += 4) {
            float4 u = *reinterpret_cast<const float4*>(urow + h);
            a += u.x * hb[h] + u.y * hb[h + 1] + u.z * hb[h + 2] + u.w * hb[h + 3];
        }
        bv[r] = a;
    }
    float ss = bv[0] + bv[1] + bv[2] + bv[3];
    float qs = bv[0]*bv[0] + bv[1]*bv[1] + bv[2]*bv[2] + bv[3]*bv[3];
    #pragma unroll
    for (int off = 32; off > 0; off >>= 1) {
        ss += __shfl_xor(ss, off);
        qs += __shfl_xor(qs, off);
    }
    const float mu  = ss * (1.0f / 256.f);
    const float var = qs * (1.0f / 256.f) - mu * mu;
    const float inv = rsqrtf(var + EPS);
    #pragma unroll
    for (int r = 0; r < 4; ++r)
        blnbf[(size_t)t * 256 + l * 4 + r] = f2b((bv[r] - mu) * inv);
}

// ===========================================================================
// k_main — G-GEMM + fused epilogue.
// FIX (R10): chunk 3 lives in BUFFER 0 (stageC(3,0)) — the final compute must
// be computeA(0). R6-R9 called computeA(3): Ab[3]/Bb[3] are OUT OF BOUNDS,
// reading into hwT/BQT (deterministic garbage; absmax shifted with prep —
// the diagnostic that located this).
// ===========================================================================
__global__ __launch_bounds__(256, 2)
void k_main(const unsigned short* __restrict__ BW,
            const unsigned short* __restrict__ BQ,
            const unsigned short* __restrict__ xbf,
            const unsigned short* __restrict__ hwbf,
            const float* __restrict__ sxf,
            const float* __restrict__ qb2f,
            const float* __restrict__ sb2f,
            const unsigned short* __restrict__ blnbf,
            float* __restrict__ y)
{
    __shared__ __align__(16) unsigned short Ab[3][64][64];   // 24576 B
    __shared__ __align__(16) unsigned short Bb[3][82][64];   // 31488 B (rows 66..80 zero)
    __shared__ __align__(16) unsigned short hwT[64][32];     //  4096 B
    __shared__ __align__(16) unsigned short BQT[82][32];     //  5248 B (rows 68..81 zero)
    __shared__ float scr[3][64][2];                          //  1536 B

    const int tid = threadIdx.x, lane = tid & 63, wave = tid >> 6;
    const int c = lane & 15, g = lane >> 4;
    const int wr = wave >> 1, wc = wave & 1;
    const int b = blockIdx.x;
    const int og = b >> 5, tt = b & 31;
    const int t0 = tt * 64;

    // ---- prologue: zero pads ----
    {
        uint4 z = make_uint4(0, 0, 0, 0);
        for (int k = 0; k < 2; ++k) {
            int u = tid + k * 256;
            if (u < 360) {  // Bb rows 66..80, 3 bufs: 15*8=120 units each
                int bu = u / 120, v = u - bu * 120;
                *(uint4*)((unsigned short*)&Bb[bu][0][0] + (528 + v) * 8) = z;
            }
        }
        if (tid < 56)  // BQT rows 68..81: 14*4 units
            *(uint4*)((unsigned short*)&BQT[0][0] + (272 + tid) * 8) = z;
    }
    // ---- static stages: hwT (1 instr/wave), BQT (2 instr/wave) ----
    {
        int u = wave * 64 + lane;      // 256 units
        gll16(hwbf + (size_t)(t0 + (u >> 2)) * 32 + (u & 3) * 8,
              (unsigned short*)&hwT[0][0] + u * 8);
    }
    for (int k = 0; k < 2; ++k) {      // 272 units, 68/wave
        int u = wave * 68 + k * 64 + lane;
        if (u < wave * 68 + 68) {
            int rr = u >> 2, s = u & 3;
            int ol = rr >= 34 ? 1 : 0, rl = rr - 34 * ol;
            gll16(BQ + ((size_t)(og * 2 + ol) * 34 + rl) * 32 + s * 8,
                  (unsigned short*)&BQT[0][0] + u * 8);
        }
    }
    // ---- chunk stage: 5 instr/wave/chunk (A:2, B:3) ----
    auto stageC = [&](int kc, int buf) {
        #pragma unroll
        for (int k = 0; k < 2; ++k) {  // A: 512 units, 128/wave
            int u = wave * 128 + k * 64 + lane;
            int r = u >> 3, s = u & 7;
            gll16(xbf + (size_t)(t0 + r) * 256 + kc * 64 + ((s ^ (r & 7)) * 8),
                  (unsigned short*)&Ab[buf][0][0] + u * 8);
        }
        #pragma unroll
        for (int k = 0; k < 3; ++k) {  // B: 528 units, 132/wave
            int u = wave * 132 + k * 64 + lane;
            if (u < wave * 132 + 132) {
                int rr = u >> 3, s = u & 7;
                int ol = rr >= 33 ? 1 : 0, rl = rr - 33 * ol;
                gll16(BW + ((size_t)(og * 2 + ol) * 33 + rl) * 256 + kc * 64 + ((s ^ (rr & 7)) * 8),
                      (unsigned short*)&Bb[buf][0][0] + u * 8);
            }
        }
    };

    f32x4 acc1[2][3], acc2[2][3];
    #pragma unroll
    for (int mt = 0; mt < 2; ++mt)
        #pragma unroll
        for (int nb = 0; nb < 3; ++nb) {
            acc1[mt][nb] = (f32x4){0,0,0,0};
            acc2[mt][nb] = (f32x4){0,0,0,0};
        }

    auto computeA = [&](int buf) {
        short8 a[2][2], bb[3][2];
        #pragma unroll
        for (int mt = 0; mt < 2; ++mt) {
            int row = wr * 32 + mt * 16 + c;
            #pragma unroll
            for (int ku = 0; ku < 2; ++ku)
                a[mt][ku] = *(const short8*)&Ab[buf][row][(((ku*4+g) ^ (c & 7)) * 8)];
        }
        #pragma unroll
        for (int nb = 0; nb < 3; ++nb) {
            int h = nb * 16 + c;
            int rr = (h < 33) ? (wc * 33 + h) : (66 + h - 33);
            #pragma unroll
            for (int ku = 0; ku < 2; ++ku)
                bb[nb][ku] = *(const short8*)&Bb[buf][rr][(((ku*4+g) ^ (rr & 7)) * 8)];
        }
        #pragma unroll
        for (int ku = 0; ku < 2; ++ku)
            #pragma unroll
            for (int mt = 0; mt < 2; ++mt)
                #pragma unroll
                for (int nb = 0; nb < 3; ++nb)
                    acc1[mt][nb] = __builtin_amdgcn_mfma_f32_16x16x32_bf16(
                        a[mt][ku], bb[nb][ku], acc1[mt][nb], 0, 0, 0);
    };

    stageC(0, 0); stageC(1, 1);
    asm volatile("s_waitcnt vmcnt(5)" ::: "memory");  // this wave: static+chunk0 done
    __syncthreads();                                  // => all waves' chunk0 visible

    stageC(2, 2);
    computeA(0);                                      // chunk0 from buf0
    __builtin_amdgcn_s_barrier();                     // all waves done reading buf0
    stageC(3, 0);                                     // chunk3 -> buf0
    asm volatile("s_waitcnt vmcnt(10)" ::: "memory"); // this wave: chunk1 done
    __builtin_amdgcn_s_barrier();                     // => all waves' chunk1 visible
    computeA(1);                                      // chunk1 from buf1
    asm volatile("s_waitcnt vmcnt(5)" ::: "memory");  // this wave: chunk2 done
    __builtin_amdgcn_s_barrier();                     // => all waves' chunk2 visible
    computeA(2);                                      // chunk2 from buf2
    asm volatile("s_waitcnt vmcnt(0)" ::: "memory");  // this wave: chunk3 done
    __builtin_amdgcn_s_barrier();                     // => all waves' chunk3 visible
    computeA(0);                                      // chunk3 from buf0  (R10 FIX)

    // ---- GEMM-B: K=32, one step ----
    {
        short8 a2[2], bq[3];
        #pragma unroll
        for (int mt = 0; mt < 2; ++mt)
            a2[mt] = *(const short8*)&hwT[wr * 32 + mt * 16 + c][g * 8];
        #pragma unroll
        for (int nb = 0; nb < 3; ++nb) {
            int h = nb * 16 + c;
            int rr = (h < 34) ? (wc * 34 + h) : (68 + h - 34);
            bq[nb] = *(const short8*)&BQT[rr][g * 8];
        }
        #pragma unroll
        for (int mt = 0; mt < 2; ++mt)
            #pragma unroll
            for (int nb = 0; nb < 3; ++nb)
                acc2[mt][nb] = __builtin_amdgcn_mfma_f32_16x16x32_bf16(
                    a2[mt], bq[nb], acc2[mt][nb], 0, 0, 0);
    }

    // ---- epilogue: hw-weighted contraction over h ----
    #pragma unroll
    for (int mt = 0; mt < 2; ++mt) {
        float hwa[4], hwb[4];
        #pragma unroll
        for (int j = 0; j < 4; ++j) {
            int tl = wr * 32 + mt * 16 + g * 4 + j;
            hwa[j] = b2f(hwT[tl][c]);
            hwb[j] = b2f(hwT[tl][16 + c]);
        }
        float vdw[4], vqq[4], vsw[4];
        #pragma unroll
        for (int j = 0; j < 4; ++j) {
            vdw[j] = acc1[mt][0][j] * hwa[j] + acc1[mt][1][j] * hwb[j] + acc1[mt][2][j];
            float q2t = (c == 1) ? 0.0f : acc2[mt][2][j];   // exclude S2 col from qq
            vqq[j] = acc2[mt][0][j] * hwa[j] + acc2[mt][1][j] * hwb[j] + q2t;
            vsw[j] = acc2[mt][2][j];                        // valid at c==1 (S2 col)
        }
        #pragma unroll
        for (int off = 1; off <= 8; off <<= 1)
            #pragma unroll
            for (int j = 0; j < 4; ++j) {
                vdw[j] += __shfl_xor(vdw[j], off);
                vqq[j] += __shfl_xor(vqq[j], off);
            }
        #pragma unroll
        for (int j = 0; j < 4; ++j) {
            int tl = wr * 32 + mt * 16 + g * 4 + j;
            if (c == 0) { scr[0][tl][wc] = vdw[j]; scr[1][tl][wc] = vqq[j]; }
            if (c == 1) { scr[2][tl][wc] = vsw[j]; }
        }
    }
    __syncthreads();

    // ---- final LN + y ----
    if (tid < 128) {
        int tl = tid >> 1, ol = tid & 1;
        int t = t0 + tl, o = og * 2 + ol;
        float dw = scr[0][tl][ol];
        float qq = scr[1][tl][ol] + qb2f[o];
        float sw = scr[2][tl][ol] + sb2f[o];
        float mu  = sw * (1.0f / 256.f);
        float var = qq * (1.0f / 256.f) - mu * mu;
        float inv = rsqrtf(var + EPS);
        float bl = b2f(blnbf[(size_t)t * 256 + o]);
        y[(size_t)t * 256 + o] = inv * (dw - mu * sxf[t]) + bl;
    }
}

// ---------------------------------------------------------------------------
extern "C" void kernel_launch(void* const* d_in, const int* in_sizes, int n_in,
                              void* d_out, int out_size, void* d_ws, size_t ws_size,
                              hipStream_t stream)
{
    (void)in_sizes; (void)n_in; (void)out_size; (void)ws_size;
    const float* x  = (const float*)d_in[0];
    const float* w1 = (const float*)d_in[1];
    const float* b1 = (const float*)d_in[2];
    const float* w2 = (const float*)d_in[3];
    const float* b2 = (const float*)d_in[4];
    const float* u1 = (const float*)d_in[5];
    const float* c1 = (const float*)d_in[6];
    const float* u2 = (const float*)d_in[7];
    const float* c2 = (const float*)d_in[8];
    float* y = (float*)d_out;

    char* ws = (char*)d_ws;
    unsigned short* BW    = (unsigned short*)(ws);                 // 4,325,376
    unsigned short* BQ    = (unsigned short*)(ws + 4325376);       //   557,056
    unsigned short* xbf   = (unsigned short*)(ws + 4882432);       // 1,048,576
    unsigned short* hwbf  = (unsigned short*)(ws + 5931008);       //   131,072
    float*          sxf   = (float*)         (ws + 6062080);       //     8,192
    float*          qb2f  = (float*)         (ws + 6070272);       //     1,024
    float*          sb2f  = (float*)         (ws + 6071296);       //     1,024
    unsigned short* blnbf = (unsigned short*)(ws + 6072320);       // 1,048,576 -> 7,120,896

    k_prep<<<256, 256, 0, stream>>>(w2, b2, BW, BQ, qb2f, sb2f);
    ka_hw_bias<<<2048, 64, 0, stream>>>(x, w1, b1, u1, c1, u2, c2, xbf, hwbf, sxf, blnbf);
    k_main<<<4096, 256, 0, stream>>>(BW, BQ, xbf, hwbf, sxf, qb2f, sb2f, blnbf, y);
}

// Round 11
// 69.052 us; speedup vs baseline: 1.3195x; 1.3195x over previous
//
#include <hip/hip_runtime.h>
#include <hip/hip_bf16.h>
#include <stdint.h>

#define EPS 1e-5f

typedef __attribute__((ext_vector_type(8))) short short8;
typedef __attribute__((ext_vector_type(4))) float f32x4;

typedef const __attribute__((address_space(1))) uint32_t gas_u32;
typedef __attribute__((address_space(3))) uint32_t las_u32;

static __device__ __forceinline__ void gll16(const void* src, void* dst) {
    __builtin_amdgcn_global_load_lds((gas_u32*)src, (las_u32*)dst, 16, 0, 0);
}
static __device__ __forceinline__ unsigned short f2b(float f) {
    __hip_bfloat16 h = __float2bfloat16(f);
    return *reinterpret_cast<unsigned short*>(&h);
}
static __device__ __forceinline__ float b2f(unsigned short u) {
    union { unsigned int i; float f; } x; x.i = ((unsigned int)u) << 16; return x.f;
}
static __device__ __forceinline__ unsigned int pk2(float a, float b) {
    return (unsigned int)f2b(a) | ((unsigned int)f2b(b) << 16);
}

// ===========================================================================
// k_pre dispatcher: blocks 0..255 = prep(o) (R10-verbatim), 256..767 = ka (4 tok)
// ===========================================================================
__device__ void prep_body(int o, const float* __restrict__ w2,
                          const float* __restrict__ b2,
                          unsigned short* __restrict__ BW,
                          unsigned short* __restrict__ BQ,
                          float* __restrict__ qb2f, float* __restrict__ sb2f,
                          char* smem)
{
    float* w2s = (float*)smem;        // [256][32]
    float* b2s = w2s + 8192;          // [256]

    const int tid = threadIdx.x, lane = tid & 63, wave = tid >> 6;
    const float* w2o = w2 + (size_t)o * 8192;

    #pragma unroll
    for (int q = 0; q < 8; ++q) {
        int I = wave * 8 + q;
        gll16(w2o + I * 256 + lane * 4, w2s + I * 256);
    }
    if (wave == 0) gll16(b2 + (size_t)o * 256 + lane * 4, b2s);
    asm volatile("s_waitcnt vmcnt(0)" ::: "memory");
    __syncthreads();

    // BW rows: r<32: BW[o][r][i] = w2s[i][r]; r==32: b2
    for (int k = 0; k < 5; ++k) {
        int u = tid + k * 256;
        if (u < 1056) {
            int r = u >> 5, s = u & 31;
            float vv[8];
            #pragma unroll
            for (int d = 0; d < 8; ++d)
                vv[d] = (r < 32) ? w2s[(s * 8 + d) * 32 + r] : b2s[s * 8 + d];
            uint4 pk;
            pk.x = pk2(vv[0], vv[1]); pk.y = pk2(vv[2], vv[3]);
            pk.z = pk2(vv[4], vv[5]); pk.w = pk2(vv[6], vv[7]);
            *(uint4*)&BW[((size_t)o * 33 + r) * 256 + s * 8] = pk;
        }
    }

    // BQ rows 0..31: Q2[hp][h] = sum_i W2[i,hp] W2[i,h]
    {
        const int h = tid & 31, hp0 = tid >> 5;
        float acc[4] = {0.f, 0.f, 0.f, 0.f};
        for (int i = 0; i < 256; ++i) {
            float wh = w2s[i * 32 + h];
            #pragma unroll
            for (int k = 0; k < 4; ++k)
                acc[k] += w2s[i * 32 + hp0 + 8 * k] * wh;
        }
        #pragma unroll
        for (int k = 0; k < 4; ++k)
            BQ[((size_t)o * 34 + (hp0 + 8 * k)) * 32 + h] = f2b(acc[k]);
    }

    // BQ row 32 = 2*P2, row 33 = S2; qb2/sb2 scalars
    if (tid < 32) {
        float pa = 0.f, sa = 0.f;
        for (int i = 0; i < 256; ++i) {
            float wv = w2s[i * 32 + tid];
            pa += wv * b2s[i];
            sa += wv;
        }
        BQ[((size_t)o * 34 + 32) * 32 + tid] = f2b(2.0f * pa);
        BQ[((size_t)o * 34 + 33) * 32 + tid] = f2b(sa);
    } else if (tid == 32) {
        float sb = 0.f, qb = 0.f;
        for (int i = 0; i < 256; ++i) { float bv = b2s[i]; sb += bv; qb += bv * bv; }
        sb2f[o] = sb;
        qb2f[o] = qb;
    }
}

__device__ void ka_body4(int tb, const float* __restrict__ x,
                         const float* __restrict__ w1, const float* __restrict__ b1,
                         const float* __restrict__ u1, const float* __restrict__ c1,
                         const float* __restrict__ u2, const float* __restrict__ c2,
                         unsigned short* __restrict__ xbf,
                         unsigned short* __restrict__ hwbf,
                         float* __restrict__ sxf,
                         unsigned short* __restrict__ blnbf,
                         char* smem)
{
    const int tid = threadIdx.x, l = tid & 63, wave = tid >> 6;
    const int t = tb * 4 + wave;

    float* xs = (float*)smem + wave * 288;
    float* hb = xs + 256;

    float4 x4 = reinterpret_cast<const float4*>(x + (size_t)t * 256)[l];
    reinterpret_cast<float4*>(xs)[l] = x4;

    float s = x4.x + x4.y + x4.z + x4.w;
    #pragma unroll
    for (int off = 32; off > 0; off >>= 1) s += __shfl_xor(s, off);
    if (l == 0) sxf[t] = s;

    {
        ushort4 ux;
        ux.x = f2b(x4.x); ux.y = f2b(x4.y); ux.z = f2b(x4.z); ux.w = f2b(x4.w);
        *reinterpret_cast<ushort4*>(xbf + (size_t)t * 256 + l * 4) = ux;
    }
    __syncthreads();

    const float* wrow = (l < 32) ? (w1 + (size_t)l * 256) : (u1 + (size_t)(l - 32) * 256);
    float acc = (l < 32) ? b1[l] : c1[l - 32];
    #pragma unroll 8
    for (int i = 0; i < 256; i += 4) {
        float4 w = *reinterpret_cast<const float4*>(wrow + i);
        acc += w.x * xs[i] + w.y * xs[i + 1] + w.z * xs[i + 2] + w.w * xs[i + 3];
    }
    if (l < 32) hwbf[(size_t)t * 32 + l] = f2b(acc);
    else        hb[l - 32] = acc;
    __syncthreads();

    float bv[4];
    #pragma unroll
    for (int r = 0; r < 4; ++r) {
        const int oo = l * 4 + r;
        const float* urow = u2 + (size_t)oo * 32;
        float a = c2[oo];
        #pragma unroll
        for (int h = 0; h < 32; h += 4) {
            float4 u = *reinterpret_cast<const float4*>(urow + h);
            a += u.x * hb[h] + u.y * hb[h + 1] + u.z * hb[h + 2] + u.w * hb[h + 3];
        }
        bv[r] = a;
    }
    float ss = bv[0] + bv[1] + bv[2] + bv[3];
    float qs = bv[0]*bv[0] + bv[1]*bv[1] + bv[2]*bv[2] + bv[3]*bv[3];
    #pragma unroll
    for (int off = 32; off > 0; off >>= 1) {
        ss += __shfl_xor(ss, off);
        qs += __shfl_xor(qs, off);
    }
    const float mu  = ss * (1.0f / 256.f);
    const float var = qs * (1.0f / 256.f) - mu * mu;
    const float inv = rsqrtf(var + EPS);
    #pragma unroll
    for (int r = 0; r < 4; ++r)
        blnbf[(size_t)t * 256 + l * 4 + r] = f2b((bv[r] - mu) * inv);
}

__global__ __launch_bounds__(256)
void k_pre(const float* __restrict__ x,
           const float* __restrict__ w1, const float* __restrict__ b1,
           const float* __restrict__ w2, const float* __restrict__ b2,
           const float* __restrict__ u1, const float* __restrict__ c1,
           const float* __restrict__ u2, const float* __restrict__ c2,
           unsigned short* __restrict__ BW, unsigned short* __restrict__ BQ,
           float* __restrict__ qb2f, float* __restrict__ sb2f,
           unsigned short* __restrict__ xbf, unsigned short* __restrict__ hwbf,
           float* __restrict__ sxf, unsigned short* __restrict__ blnbf)
{
    __shared__ __align__(16) char smem[33792];
    const int b = blockIdx.x;
    if (b < 256) prep_body(b, w2, b2, BW, BQ, qb2f, sb2f, smem);
    else         ka_body4(b - 256, x, w1, b1, u1, c1, u2, c2, xbf, hwbf, sxf, blnbf, smem);
}

// ===========================================================================
// k_main R11: block = 64 tokens x 16 o's. A (x-chunk) staged ONCE, 8-iteration
// og loop re-uses it; B double-buffered per k-chunk (parity = kc&1), counted
// vmcnt THEN barrier. A-frags / GEMM-B A-operand / epilogue hw-scalars hoisted.
// Grid 512 = 2 blocks/CU (LDS 69.9 KB). og_grp = b&15 -> 2 B-slices per XCD L2.
// ===========================================================================
__global__ __launch_bounds__(256, 2)
void k_main(const unsigned short* __restrict__ BW,
            const unsigned short* __restrict__ BQ,
            const unsigned short* __restrict__ xbf,
            const unsigned short* __restrict__ hwbf,
            const float* __restrict__ sxf,
            const float* __restrict__ qb2f,
            const float* __restrict__ sb2f,
            const unsigned short* __restrict__ blnbf,
            float* __restrict__ y)
{
    __shared__ __align__(16) unsigned short Ash[64 * 256];    // 32768 B
    __shared__ __align__(16) unsigned short Bb[2][82 * 64];   // 20992 B (rows 66..81 zero)
    __shared__ __align__(16) unsigned short hwT[64 * 32];     //  4096 B
    __shared__ __align__(16) unsigned short BQT[2][82 * 32];  // 10496 B (rows 68..81 zero)
    __shared__ float scr[3][64][2];                           //  1536 B

    const int tid = threadIdx.x, lane = tid & 63, wave = tid >> 6;
    const int c = lane & 15, g = lane >> 4;
    const int wr = wave >> 1, wc = wave & 1;
    const int b = blockIdx.x;
    const int og_grp = b & 15, tt = b >> 4;
    const int t0 = tt * 64;
    const int obase = og_grp * 16;     // 16 o's per block

    // ---- zero pads (Bb rows 66..81 both bufs; BQT rows 68..81 both bufs) ----
    {
        uint4 z = make_uint4(0, 0, 0, 0);
        { int bu = tid >> 7, j = tid & 127;            // 256 units
          *(uint4*)&Bb[bu][(528 + j) * 8] = z; }
        if (tid < 112) { int bu = tid / 56, j = tid % 56;
          *(uint4*)&BQT[bu][(272 + j) * 8] = z; }
    }
    // ---- static stages: hwT (1/wave), A all 4 k-chunks (8/wave, swizzled) ----
    {
        int u = wave * 64 + lane;
        gll16(hwbf + (size_t)(t0 + (u >> 2)) * 32 + (u & 3) * 8,
              (unsigned short*)hwT + u * 8);
    }
    #pragma unroll
    for (int k = 0; k < 8; ++k) {
        int u = wave * 512 + k * 64 + lane;
        int r = u >> 5, s = u & 31, kc = s >> 3, s8 = s & 7;
        gll16(xbf + (size_t)(t0 + r) * 256 + kc * 64 + ((s8 ^ (r & 7)) * 8),
              Ash + u * 8);
    }

    auto stageBQT = [&](int o2, int bq) {   // 2 instr/wave
        #pragma unroll
        for (int k = 0; k < 2; ++k) {
            int u = wave * 68 + k * 64 + lane;
            if (u < wave * 68 + 68) {
                int rr = u >> 2, s = u & 3;
                int ol = rr >= 34 ? 1 : 0, rl = rr - 34 * ol;
                gll16(BQ + ((size_t)(o2 + ol) * 34 + rl) * 32 + s * 8,
                      (unsigned short*)BQT[bq] + u * 8);
            }
        }
    };
    auto stageB = [&](int o2, int kc, int bf) {   // 3 instr/wave
        #pragma unroll
        for (int k = 0; k < 3; ++k) {
            int u = wave * 132 + k * 64 + lane;
            if (u < wave * 132 + 132) {
                int rr = u >> 3, s = u & 7;
                int ol = rr >= 33 ? 1 : 0, rl = rr - 33 * ol;
                gll16(BW + ((size_t)(o2 + ol) * 33 + rl) * 256 + kc * 64 + ((s ^ (rr & 7)) * 8),
                      (unsigned short*)Bb[bf] + u * 8);
            }
        }
    };

    // ---- prologue: BQT(og0) + B(og0,kc0); drain all but newest 3 ----
    stageBQT(obase, 0);
    stageB(obase, 0, 0);
    asm volatile("s_waitcnt vmcnt(3)" ::: "memory");   // A+hwT+BQT0 drained; B00 (3) may remain
    __syncthreads();

    // ---- hoist per-block register state ----
    short8 afr[2][2][4];   // [mt][ku][kc]
    #pragma unroll
    for (int mt = 0; mt < 2; ++mt) {
        const int row = wr * 32 + mt * 16 + c;
        #pragma unroll
        for (int kc = 0; kc < 4; ++kc)
            #pragma unroll
            for (int ku = 0; ku < 2; ++ku)
                afr[mt][ku][kc] = *(const short8*)&Ash[row * 256 + kc * 64 + (((ku * 4 + g) ^ (c & 7)) * 8)];
    }
    short8 a2f[2];
    a2f[0] = *(const short8*)&hwT[(wr * 32 + c) * 32 + g * 8];
    a2f[1] = *(const short8*)&hwT[(wr * 32 + 16 + c) * 32 + g * 8];
    float hwa[2][4], hwb[2][4];
    #pragma unroll
    for (int mt = 0; mt < 2; ++mt)
        #pragma unroll
        for (int j = 0; j < 4; ++j) {
            int tl = wr * 32 + mt * 16 + g * 4 + j;
            hwa[mt][j] = b2f(hwT[tl * 32 + c]);
            hwb[mt][j] = b2f(hwT[tl * 32 + 16 + c]);
        }

    // ---- og loop: 8 iterations x 4 k-chunks ----
    for (int og = 0; og < 8; ++og) {
        const int o2 = obase + og * 2;
        f32x4 acc1[2][3], acc2[2][3];
        #pragma unroll
        for (int mt = 0; mt < 2; ++mt)
            #pragma unroll
            for (int nb = 0; nb < 3; ++nb) {
                acc1[mt][nb] = (f32x4){0, 0, 0, 0};
                acc2[mt][nb] = (f32x4){0, 0, 0, 0};
            }

        #pragma unroll
        for (int kc = 0; kc < 4; ++kc) {
            // issue next-chunk staging, then counted vmcnt + barrier
            if (kc < 3) {
                stageB(o2, kc + 1, (kc + 1) & 1);
                asm volatile("s_waitcnt vmcnt(3)" ::: "memory");
            } else if (og < 7) {
                stageB(o2 + 2, 0, 0);          // next og's kc0 -> buf0
                stageBQT(o2 + 2, (og + 1) & 1);
                asm volatile("s_waitcnt vmcnt(5)" ::: "memory");
            } else {
                asm volatile("s_waitcnt vmcnt(0)" ::: "memory");
            }
            __builtin_amdgcn_s_barrier();

            // compute chunk kc from Bb[kc&1]
            {
                const unsigned short* Bbuf = (const unsigned short*)Bb[kc & 1];
                short8 bb[3][2];
                #pragma unroll
                for (int nb = 0; nb < 3; ++nb) {
                    int h = nb * 16 + c;
                    int rr = (h < 33) ? (wc * 33 + h) : (66 + h - 33);
                    #pragma unroll
                    for (int ku = 0; ku < 2; ++ku)
                        bb[nb][ku] = *(const short8*)&Bbuf[rr * 64 + (((ku * 4 + g) ^ (rr & 7)) * 8)];
                }
                #pragma unroll
                for (int ku = 0; ku < 2; ++ku)
                    #pragma unroll
                    for (int mt = 0; mt < 2; ++mt)
                        #pragma unroll
                        for (int nb = 0; nb < 3; ++nb)
                            acc1[mt][nb] = __builtin_amdgcn_mfma_f32_16x16x32_bf16(
                                afr[mt][ku][kc], bb[nb][ku], acc1[mt][nb], 0, 0, 0);
            }
            __builtin_amdgcn_s_barrier();
        }

        // ---- GEMM-B: K=32, one step (BQT[og&1]) ----
        {
            const unsigned short* Q = (const unsigned short*)BQT[og & 1];
            short8 bq[3];
            #pragma unroll
            for (int nb = 0; nb < 3; ++nb) {
                int h = nb * 16 + c;
                int rr = (h < 34) ? (wc * 34 + h) : (68 + h - 34);
                bq[nb] = *(const short8*)&Q[rr * 32 + g * 8];
            }
            #pragma unroll
            for (int mt = 0; mt < 2; ++mt)
                #pragma unroll
                for (int nb = 0; nb < 3; ++nb)
                    acc2[mt][nb] = __builtin_amdgcn_mfma_f32_16x16x32_bf16(
                        a2f[mt], bq[nb], acc2[mt][nb], 0, 0, 0);
        }

        // ---- epilogue: hw-weighted contraction over h ----
        #pragma unroll
        for (int mt = 0; mt < 2; ++mt) {
            float vdw[4], vqq[4], vsw[4];
            #pragma unroll
            for (int j = 0; j < 4; ++j) {
                vdw[j] = acc1[mt][0][j] * hwa[mt][j] + acc1[mt][1][j] * hwb[mt][j] + acc1[mt][2][j];
                float q2t = (c == 1) ? 0.0f : acc2[mt][2][j];
                vqq[j] = acc2[mt][0][j] * hwa[mt][j] + acc2[mt][1][j] * hwb[mt][j] + q2t;
                vsw[j] = acc2[mt][2][j];
            }
            #pragma unroll
            for (int off = 1; off <= 8; off <<= 1)
                #pragma unroll
                for (int j = 0; j < 4; ++j) {
                    vdw[j] += __shfl_xor(vdw[j], off);
                    vqq[j] += __shfl_xor(vqq[j], off);
                }
            #pragma unroll
            for (int j = 0; j < 4; ++j) {
                int tl = wr * 32 + mt * 16 + g * 4 + j;
                if (c == 0) { scr[0][tl][wc] = vdw[j]; scr[1][tl][wc] = vqq[j]; }
                if (c == 1) { scr[2][tl][wc] = vsw[j]; }
            }
        }
        __syncthreads();

        if (tid < 128) {
            int tl = tid >> 1, ol = tid & 1;
            int t = t0 + tl, o = o2 + ol;
            float dw = scr[0][tl][ol];
            float qq = scr[1][tl][ol] + qb2f[o];
            float sw = scr[2][tl][ol] + sb2f[o];
            float mu  = sw * (1.0f / 256.f);
            float var = qq * (1.0f / 256.f) - mu * mu;
            float inv = rsqrtf(var + EPS);
            float bl = b2f(blnbf[(size_t)t * 256 + o]);
            y[(size_t)t * 256 + o] = inv * (dw - mu * sxf[t]) + bl;
        }
        __syncthreads();   // scr reuse + Bb[0] overwrite protection for next og
    }
}

// ---------------------------------------------------------------------------
extern "C" void kernel_launch(void* const* d_in, const int* in_sizes, int n_in,
                              void* d_out, int out_size, void* d_ws, size_t ws_size,
                              hipStream_t stream)
{
    (void)in_sizes; (void)n_in; (void)out_size; (void)ws_size;
    const float* x  = (const float*)d_in[0];
    const float* w1 = (const float*)d_in[1];
    const float* b1 = (const float*)d_in[2];
    const float* w2 = (const float*)d_in[3];
    const float* b2 = (const float*)d_in[4];
    const float* u1 = (const float*)d_in[5];
    const float* c1 = (const float*)d_in[6];
    const float* u2 = (const float*)d_in[7];
    const float* c2 = (const float*)d_in[8];
    float* y = (float*)d_out;

    char* ws = (char*)d_ws;
    unsigned short* BW    = (unsigned short*)(ws);                 // 4,325,376
    unsigned short* BQ    = (unsigned short*)(ws + 4325376);       //   557,056
    unsigned short* xbf   = (unsigned short*)(ws + 4882432);       // 1,048,576
    unsigned short* hwbf  = (unsigned short*)(ws + 5931008);       //   131,072
    float*          sxf   = (float*)         (ws + 6062080);       //     8,192
    float*          qb2f  = (float*)         (ws + 6070272);       //     1,024
    float*          sb2f  = (float*)         (ws + 6071296);       //     1,024
    unsigned short* blnbf = (unsigned short*)(ws + 6072320);       // 1,048,576 -> 7,120,896

    k_pre<<<768, 256, 0, stream>>>(x, w1, b1, w2, b2, u1, c1, u2, c2,
                                   BW, BQ, qb2f, sb2f, xbf, hwbf, sxf, blnbf);
    k_main<<<512, 256, 0, stream>>>(BW, BQ, xbf, hwbf, sxf, qb2f, sb2f, blnbf, y);
}

// Round 12
// 67.883 us; speedup vs baseline: 1.3423x; 1.0172x over previous
//
#include <hip/hip_runtime.h>
#include <hip/hip_bf16.h>
#include <stdint.h>

#define EPS 1e-5f

typedef __attribute__((ext_vector_type(8))) short short8;
typedef __attribute__((ext_vector_type(4))) float f32x4;

typedef const __attribute__((address_space(1))) uint32_t gas_u32;
typedef __attribute__((address_space(3))) uint32_t las_u32;

static __device__ __forceinline__ void gll16(const void* src, void* dst) {
    __builtin_amdgcn_global_load_lds((gas_u32*)src, (las_u32*)dst, 16, 0, 0);
}
static __device__ __forceinline__ unsigned short f2b(float f) {
    __hip_bfloat16 h = __float2bfloat16(f);
    return *reinterpret_cast<unsigned short*>(&h);
}
static __device__ __forceinline__ float b2f(unsigned short u) {
    union { unsigned int i; float f; } x; x.i = ((unsigned int)u) << 16; return x.f;
}
static __device__ __forceinline__ unsigned int pk2(float a, float b) {
    return (unsigned int)f2b(a) | ((unsigned int)f2b(b) << 16);
}

// ===========================================================================
// prep_body R12: mT (slot-swizzled bf16 transpose) + MFMA Gram.
// Replaces R11's scalar Q2 (~1500 dep. ops/thread) with 8-24 MFMAs/wave.
// Algebra re-verified against the (now bug-fixed) k_main fragment layouts.
// ===========================================================================
__device__ void prep_body(int o, const float* __restrict__ w2,
                          const float* __restrict__ b2,
                          unsigned short* __restrict__ BW,
                          unsigned short* __restrict__ BQ,
                          float* __restrict__ qb2f, float* __restrict__ sb2f,
                          char* smem)
{
    float* w2s = (float*)smem;                               // [256][32] 32768 B
    float* b2s = w2s + 8192;                                 // [256]      1024 B
    unsigned short* mT = (unsigned short*)(b2s + 256);       // [34][256] 17408 B

    const int tid = threadIdx.x, lane = tid & 63, wave = tid >> 6;
    const int c = lane & 15, g = lane >> 4;
    const float* w2o = w2 + (size_t)o * 8192;

    #pragma unroll
    for (int q = 0; q < 8; ++q) {
        int I = wave * 8 + q;
        gll16(w2o + I * 256 + lane * 4, w2s + I * 256);
    }
    if (wave == 0) gll16(b2 + (size_t)o * 256 + lane * 4, b2s);
    asm volatile("s_waitcnt vmcnt(0)" ::: "memory");
    __syncthreads();

    // mT rows 0..31: column gather (transpose) -> bf16, slot-swizzled (key r&7)
    {
        const int hp = tid >> 3, oct = tid & 7;
        float v[32];
        #pragma unroll
        for (int k = 0; k < 32; ++k) v[k] = w2s[(oct * 32 + k) * 32 + hp];
        #pragma unroll
        for (int q = 0; q < 4; ++q) {
            uint4 pk;
            pk.x = pk2(v[q*8+0], v[q*8+1]);
            pk.y = pk2(v[q*8+2], v[q*8+3]);
            pk.z = pk2(v[q*8+4], v[q*8+5]);
            pk.w = pk2(v[q*8+6], v[q*8+7]);
            *(uint4*)&mT[hp * 256 + (((oct*4+q) ^ (hp & 7)) * 8)] = pk;
        }
    }
    // row 32 = ones (key 32&7=0), row 33 = b2 (key 33&7=1)
    if (tid < 32) {
        uint4 ones = make_uint4(0x3F803F80u, 0x3F803F80u, 0x3F803F80u, 0x3F803F80u);
        *(uint4*)&mT[32 * 256 + tid * 8] = ones;
    } else if (tid < 64) {
        int s = tid - 32;
        uint4 pk;
        pk.x = pk2(b2s[s*8+0], b2s[s*8+1]);
        pk.y = pk2(b2s[s*8+2], b2s[s*8+3]);
        pk.z = pk2(b2s[s*8+4], b2s[s*8+5]);
        pk.w = pk2(b2s[s*8+6], b2s[s*8+7]);
        *(uint4*)&mT[33 * 256 + ((s ^ 1) * 8)] = pk;
    }
    __syncthreads();

    // BW out: rows 0..31 from mT rows 0..31, row 32 (b2) from mT[33]
    for (int k = 0; k < 5; ++k) {
        int u = tid + k * 256;
        if (u < 1056) {
            int r = u >> 5, s = u & 31;
            int sr = (r < 32) ? r : 33;
            uint4 v = *(const uint4*)&mT[sr * 256 + ((s ^ (sr & 7)) * 8)];
            *(uint4*)&BW[((size_t)o * 33 + r) * 256 + s * 8] = v;
        }
    }

    // Gram via MFMA (fragment layout identical to verified k_main computeA)
    auto FA = [&](int a, int kk) -> short8 {
        int row = a * 16 + c;
        short8 z = {0,0,0,0,0,0,0,0};
        if (row < 34)
            return *(const short8*)&mT[row * 256 + (((kk*4+g) ^ (row & 7)) * 8)];
        return z;
    };
    auto GPAIR = [&](int a, int b) -> f32x4 {
        f32x4 acc = {0,0,0,0};
        #pragma unroll
        for (int kk = 0; kk < 8; ++kk)
            acc = __builtin_amdgcn_mfma_f32_16x16x32_bf16(FA(a,kk), FA(b,kk), acc, 0,0,0);
        return acc;
    };
    auto WQ2 = [&](int a, int b, f32x4 acc) {
        #pragma unroll
        for (int j = 0; j < 4; ++j) {
            unsigned short v = f2b(acc[j]);
            int r1 = a * 16 + g * 4 + j, r2 = b * 16 + c;
            BQ[((size_t)o * 34 + r2) * 32 + r1] = v;
            BQ[((size_t)o * 34 + r1) * 32 + r2] = v;
        }
    };
    auto WEX = [&](int a, f32x4 acc) {
        #pragma unroll
        for (int j = 0; j < 4; ++j) {
            int r1 = a * 16 + g * 4 + j;
            if (c == 0)      BQ[((size_t)o * 34 + 33) * 32 + r1] = f2b(acc[j]);        // S2
            else if (c == 1) BQ[((size_t)o * 34 + 32) * 32 + r1] = f2b(2.0f * acc[j]); // 2*P2
        }
    };
    if (wave == 0)      WQ2(0, 0, GPAIR(0, 0));
    else if (wave == 1) WQ2(0, 1, GPAIR(0, 1));
    else if (wave == 2) WQ2(1, 1, GPAIR(1, 1));
    else {
        WEX(0, GPAIR(0, 2));
        WEX(1, GPAIR(1, 2));
        f32x4 a22 = GPAIR(2, 2);
        if (g == 0 && c == 1) {
            sb2f[o] = a22[0];   // G[32][33] = sum b2
            qb2f[o] = a22[1];   // G[33][33] = sum b2^2
        }
    }
}

// ===========================================================================
// ka_body4 (R11 verbatim): 4 tokens per 256-thr block
// ===========================================================================
__device__ void ka_body4(int tb, const float* __restrict__ x,
                         const float* __restrict__ w1, const float* __restrict__ b1,
                         const float* __restrict__ u1, const float* __restrict__ c1,
                         const float* __restrict__ u2, const float* __restrict__ c2,
                         unsigned short* __restrict__ xbf,
                         unsigned short* __restrict__ hwbf,
                         float* __restrict__ sxf,
                         unsigned short* __restrict__ blnbf,
                         char* smem)
{
    const int tid = threadIdx.x, l = tid & 63, wave = tid >> 6;
    const int t = tb * 4 + wave;

    float* xs = (float*)smem + wave * 288;
    float* hb = xs + 256;

    float4 x4 = reinterpret_cast<const float4*>(x + (size_t)t * 256)[l];
    reinterpret_cast<float4*>(xs)[l] = x4;

    float s = x4.x + x4.y + x4.z + x4.w;
    #pragma unroll
    for (int off = 32; off > 0; off >>= 1) s += __shfl_xor(s, off);
    if (l == 0) sxf[t] = s;

    {
        ushort4 ux;
        ux.x = f2b(x4.x); ux.y = f2b(x4.y); ux.z = f2b(x4.z); ux.w = f2b(x4.w);
        *reinterpret_cast<ushort4*>(xbf + (size_t)t * 256 + l * 4) = ux;
    }
    __syncthreads();

    const float* wrow = (l < 32) ? (w1 + (size_t)l * 256) : (u1 + (size_t)(l - 32) * 256);
    float acc = (l < 32) ? b1[l] : c1[l - 32];
    #pragma unroll 8
    for (int i = 0; i < 256; i += 4) {
        float4 w = *reinterpret_cast<const float4*>(wrow + i);
        acc += w.x * xs[i] + w.y * xs[i + 1] + w.z * xs[i + 2] + w.w * xs[i + 3];
    }
    if (l < 32) hwbf[(size_t)t * 32 + l] = f2b(acc);
    else        hb[l - 32] = acc;
    __syncthreads();

    float bv[4];
    #pragma unroll
    for (int r = 0; r < 4; ++r) {
        const int oo = l * 4 + r;
        const float* urow = u2 + (size_t)oo * 32;
        float a = c2[oo];
        #pragma unroll
        for (int h = 0; h < 32; h += 4) {
            float4 u = *reinterpret_cast<const float4*>(urow + h);
            a += u.x * hb[h] + u.y * hb[h + 1] + u.z * hb[h + 2] + u.w * hb[h + 3];
        }
        bv[r] = a;
    }
    float ss = bv[0] + bv[1] + bv[2] + bv[3];
    float qs = bv[0]*bv[0] + bv[1]*bv[1] + bv[2]*bv[2] + bv[3]*bv[3];
    #pragma unroll
    for (int off = 32; off > 0; off >>= 1) {
        ss += __shfl_xor(ss, off);
        qs += __shfl_xor(qs, off);
    }
    const float mu  = ss * (1.0f / 256.f);
    const float var = qs * (1.0f / 256.f) - mu * mu;
    const float inv = rsqrtf(var + EPS);
    #pragma unroll
    for (int r = 0; r < 4; ++r)
        blnbf[(size_t)t * 256 + l * 4 + r] = f2b((bv[r] - mu) * inv);
}

__global__ __launch_bounds__(256)
void k_pre(const float* __restrict__ x,
           const float* __restrict__ w1, const float* __restrict__ b1,
           const float* __restrict__ w2, const float* __restrict__ b2,
           const float* __restrict__ u1, const float* __restrict__ c1,
           const float* __restrict__ u2, const float* __restrict__ c2,
           unsigned short* __restrict__ BW, unsigned short* __restrict__ BQ,
           float* __restrict__ qb2f, float* __restrict__ sb2f,
           unsigned short* __restrict__ xbf, unsigned short* __restrict__ hwbf,
           float* __restrict__ sxf, unsigned short* __restrict__ blnbf)
{
    __shared__ __align__(16) char smem[51200];
    const int b = blockIdx.x;
    if (b < 256) prep_body(b, w2, b2, BW, BQ, qb2f, sb2f, smem);
    else         ka_body4(b - 256, x, w1, b1, u1, c1, u2, c2, xbf, hwbf, sxf, blnbf, smem);
}

// ===========================================================================
// k_main (R11 verbatim): block = 64 tokens x 16 o's; A staged once, og loop;
// B double-buffered, counted vmcnt THEN barrier.
// ===========================================================================
__global__ __launch_bounds__(256, 2)
void k_main(const unsigned short* __restrict__ BW,
            const unsigned short* __restrict__ BQ,
            const unsigned short* __restrict__ xbf,
            const unsigned short* __restrict__ hwbf,
            const float* __restrict__ sxf,
            const float* __restrict__ qb2f,
            const float* __restrict__ sb2f,
            const unsigned short* __restrict__ blnbf,
            float* __restrict__ y)
{
    __shared__ __align__(16) unsigned short Ash[64 * 256];    // 32768 B
    __shared__ __align__(16) unsigned short Bb[2][82 * 64];   // 20992 B
    __shared__ __align__(16) unsigned short hwT[64 * 32];     //  4096 B
    __shared__ __align__(16) unsigned short BQT[2][82 * 32];  // 10496 B
    __shared__ float scr[3][64][2];                           //  1536 B

    const int tid = threadIdx.x, lane = tid & 63, wave = tid >> 6;
    const int c = lane & 15, g = lane >> 4;
    const int wr = wave >> 1, wc = wave & 1;
    const int b = blockIdx.x;
    const int og_grp = b & 15, tt = b >> 4;
    const int t0 = tt * 64;
    const int obase = og_grp * 16;

    {
        uint4 z = make_uint4(0, 0, 0, 0);
        { int bu = tid >> 7, j = tid & 127;
          *(uint4*)&Bb[bu][(528 + j) * 8] = z; }
        if (tid < 112) { int bu = tid / 56, j = tid % 56;
          *(uint4*)&BQT[bu][(272 + j) * 8] = z; }
    }
    {
        int u = wave * 64 + lane;
        gll16(hwbf + (size_t)(t0 + (u >> 2)) * 32 + (u & 3) * 8,
              (unsigned short*)hwT + u * 8);
    }
    #pragma unroll
    for (int k = 0; k < 8; ++k) {
        int u = wave * 512 + k * 64 + lane;
        int r = u >> 5, s = u & 31, kc = s >> 3, s8 = s & 7;
        gll16(xbf + (size_t)(t0 + r) * 256 + kc * 64 + ((s8 ^ (r & 7)) * 8),
              Ash + u * 8);
    }

    auto stageBQT = [&](int o2, int bq) {
        #pragma unroll
        for (int k = 0; k < 2; ++k) {
            int u = wave * 68 + k * 64 + lane;
            if (u < wave * 68 + 68) {
                int rr = u >> 2, s = u & 3;
                int ol = rr >= 34 ? 1 : 0, rl = rr - 34 * ol;
                gll16(BQ + ((size_t)(o2 + ol) * 34 + rl) * 32 + s * 8,
                      (unsigned short*)BQT[bq] + u * 8);
            }
        }
    };
    auto stageB = [&](int o2, int kc, int bf) {
        #pragma unroll
        for (int k = 0; k < 3; ++k) {
            int u = wave * 132 + k * 64 + lane;
            if (u < wave * 132 + 132) {
                int rr = u >> 3, s = u & 7;
                int ol = rr >= 33 ? 1 : 0, rl = rr - 33 * ol;
                gll16(BW + ((size_t)(o2 + ol) * 33 + rl) * 256 + kc * 64 + ((s ^ (rr & 7)) * 8),
                      (unsigned short*)Bb[bf] + u * 8);
            }
        }
    };

    stageBQT(obase, 0);
    stageB(obase, 0, 0);
    asm volatile("s_waitcnt vmcnt(3)" ::: "memory");
    __syncthreads();

    short8 afr[2][2][4];
    #pragma unroll
    for (int mt = 0; mt < 2; ++mt) {
        const int row = wr * 32 + mt * 16 + c;
        #pragma unroll
        for (int kc = 0; kc < 4; ++kc)
            #pragma unroll
            for (int ku = 0; ku < 2; ++ku)
                afr[mt][ku][kc] = *(const short8*)&Ash[row * 256 + kc * 64 + (((ku * 4 + g) ^ (c & 7)) * 8)];
    }
    short8 a2f[2];
    a2f[0] = *(const short8*)&hwT[(wr * 32 + c) * 32 + g * 8];
    a2f[1] = *(const short8*)&hwT[(wr * 32 + 16 + c) * 32 + g * 8];
    float hwa[2][4], hwb[2][4];
    #pragma unroll
    for (int mt = 0; mt < 2; ++mt)
        #pragma unroll
        for (int j = 0; j < 4; ++j) {
            int tl = wr * 32 + mt * 16 + g * 4 + j;
            hwa[mt][j] = b2f(hwT[tl * 32 + c]);
            hwb[mt][j] = b2f(hwT[tl * 32 + 16 + c]);
        }

    for (int og = 0; og < 8; ++og) {
        const int o2 = obase + og * 2;
        f32x4 acc1[2][3], acc2[2][3];
        #pragma unroll
        for (int mt = 0; mt < 2; ++mt)
            #pragma unroll
            for (int nb = 0; nb < 3; ++nb) {
                acc1[mt][nb] = (f32x4){0, 0, 0, 0};
                acc2[mt][nb] = (f32x4){0, 0, 0, 0};
            }

        #pragma unroll
        for (int kc = 0; kc < 4; ++kc) {
            if (kc < 3) {
                stageB(o2, kc + 1, (kc + 1) & 1);
                asm volatile("s_waitcnt vmcnt(3)" ::: "memory");
            } else if (og < 7) {
                stageB(o2 + 2, 0, 0);
                stageBQT(o2 + 2, (og + 1) & 1);
                asm volatile("s_waitcnt vmcnt(5)" ::: "memory");
            } else {
                asm volatile("s_waitcnt vmcnt(0)" ::: "memory");
            }
            __builtin_amdgcn_s_barrier();

            {
                const unsigned short* Bbuf = (const unsigned short*)Bb[kc & 1];
                short8 bb[3][2];
                #pragma unroll
                for (int nb = 0; nb < 3; ++nb) {
                    int h = nb * 16 + c;
                    int rr = (h < 33) ? (wc * 33 + h) : (66 + h - 33);
                    #pragma unroll
                    for (int ku = 0; ku < 2; ++ku)
                        bb[nb][ku] = *(const short8*)&Bbuf[rr * 64 + (((ku * 4 + g) ^ (rr & 7)) * 8)];
                }
                #pragma unroll
                for (int ku = 0; ku < 2; ++ku)
                    #pragma unroll
                    for (int mt = 0; mt < 2; ++mt)
                        #pragma unroll
                        for (int nb = 0; nb < 3; ++nb)
                            acc1[mt][nb] = __builtin_amdgcn_mfma_f32_16x16x32_bf16(
                                afr[mt][ku][kc], bb[nb][ku], acc1[mt][nb], 0, 0, 0);
            }
            __builtin_amdgcn_s_barrier();
        }

        {
            const unsigned short* Q = (const unsigned short*)BQT[og & 1];
            short8 bq[3];
            #pragma unroll
            for (int nb = 0; nb < 3; ++nb) {
                int h = nb * 16 + c;
                int rr = (h < 34) ? (wc * 34 + h) : (68 + h - 34);
                bq[nb] = *(const short8*)&Q[rr * 32 + g * 8];
            }
            #pragma unroll
            for (int mt = 0; mt < 2; ++mt)
                #pragma unroll
                for (int nb = 0; nb < 3; ++nb)
                    acc2[mt][nb] = __builtin_amdgcn_mfma_f32_16x16x32_bf16(
                        a2f[mt], bq[nb], acc2[mt][nb], 0, 0, 0);
        }

        #pragma unroll
        for (int mt = 0; mt < 2; ++mt) {
            float vdw[4], vqq[4], vsw[4];
            #pragma unroll
            for (int j = 0; j < 4; ++j) {
                vdw[j] = acc1[mt][0][j] * hwa[mt][j] + acc1[mt][1][j] * hwb[mt][j] + acc1[mt][2][j];
                float q2t = (c == 1) ? 0.0f : acc2[mt][2][j];
                vqq[j] = acc2[mt][0][j] * hwa[mt][j] + acc2[mt][1][j] * hwb[mt][j] + q2t;
                vsw[j] = acc2[mt][2][j];
            }
            #pragma unroll
            for (int off = 1; off <= 8; off <<= 1)
                #pragma unroll
                for (int j = 0; j < 4; ++j) {
                    vdw[j] += __shfl_xor(vdw[j], off);
                    vqq[j] += __shfl_xor(vqq[j], off);
                }
            #pragma unroll
            for (int j = 0; j < 4; ++j) {
                int tl = wr * 32 + mt * 16 + g * 4 + j;
                if (c == 0) { scr[0][tl][wc] = vdw[j]; scr[1][tl][wc] = vqq[j]; }
                if (c == 1) { scr[2][tl][wc] = vsw[j]; }
            }
        }
        __syncthreads();

        if (tid < 128) {
            int tl = tid >> 1, ol = tid & 1;
            int t = t0 + tl, o = o2 + ol;
            float dw = scr[0][tl][ol];
            float qq = scr[1][tl][ol] + qb2f[o];
            float sw = scr[2][tl][ol] + sb2f[o];
            float mu  = sw * (1.0f / 256.f);
            float var = qq * (1.0f / 256.f) - mu * mu;
            float inv = rsqrtf(var + EPS);
            float bl = b2f(blnbf[(size_t)t * 256 + o]);
            y[(size_t)t * 256 + o] = inv * (dw - mu * sxf[t]) + bl;
        }
        __syncthreads();
    }
}

// ---------------------------------------------------------------------------
extern "C" void kernel_launch(void* const* d_in, const int* in_sizes, int n_in,
                              void* d_out, int out_size, void* d_ws, size_t ws_size,
                              hipStream_t stream)
{
    (void)in_sizes; (void)n_in; (void)out_size; (void)ws_size;
    const float* x  = (const float*)d_in[0];
    const float* w1 = (const float*)d_in[1];
    const float* b1 = (const float*)d_in[2];
    const float* w2 = (const float*)d_in[3];
    const float* b2 = (const float*)d_in[4];
    const float* u1 = (const float*)d_in[5];
    const float* c1 = (const float*)d_in[6];
    const float* u2 = (const float*)d_in[7];
    const float* c2 = (const float*)d_in[8];
    float* y = (float*)d_out;

    char* ws = (char*)d_ws;
    unsigned short* BW    = (unsigned short*)(ws);                 // 4,325,376
    unsigned short* BQ    = (unsigned short*)(ws + 4325376);       //   557,056
    unsigned short* xbf   = (unsigned short*)(ws + 4882432);       // 1,048,576
    unsigned short* hwbf  = (unsigned short*)(ws + 5931008);       //   131,072
    float*          sxf   = (float*)         (ws + 6062080);       //     8,192
    float*          qb2f  = (float*)         (ws + 6070272);       //     1,024
    float*          sb2f  = (float*)         (ws + 6071296);       //     1,024
    unsigned short* blnbf = (unsigned short*)(ws + 6072320);       // 1,048,576 -> 7,120,896

    k_pre<<<768, 256, 0, stream>>>(x, w1, b1, w2, b2, u1, c1, u2, c2,
                                   BW, BQ, qb2f, sb2f, xbf, hwbf, sxf, blnbf);
    k_main<<<512, 256, 0, stream>>>(BW, BQ, xbf, hwbf, sxf, qb2f, sb2f, blnbf, y);
}